// Round 6
// baseline (121.670 us; speedup 1.0000x reference)
//
#include <hip/hip_runtime.h>
#include <hip/hip_bf16.h>

// InfoNCE loss, N=8192 D=512 C=128.
// Fixed-shift softmax (M=10): t_ij = s_ij/tau - 10 in [-20, 0].
//   Z_i  = sum_{class!=} e^{t_ij}
//   term = -t_p + log(Z + e^{t_p}) ~= -t_p + logZ + e^{t_p}/Z   (next term <=1e-6)
// Per-row linear partials (Z, NS, P1) accumulated in the GEMM epilogue; CNT
// from an LDS class histogram (block 0 of k_normalize).
// K2: 256^2-tile symmetric masked-exp GEMM, 4-phase/K-tile pipelined schedule:
// ring of 4 half-tile LDS slots per matrix, stage lead = 3 phases, vmcnt(4)
// before every barrier (never drains, T4), XOR-swizzled LDS (T2), setprio
// around MFMA clusters (T5), XCD-chunked block swizzle + supertile walk (T1).

constexpr int   D      = 512;
constexpr int   BT     = 256;        // tile dim
constexpr int   BK     = 64;
constexpr int   NKT    = D / BK;     // 8 K-tiles
constexpr float TAUINV = 10.0f;
constexpr float SHIFT  = 10.0f;

typedef __attribute__((ext_vector_type(8))) short bf16x8;
typedef __attribute__((ext_vector_type(4))) float f32x4;

__device__ inline ushort f2bf(float x) {
    unsigned u = __builtin_bit_cast(unsigned, x);
    unsigned r = (u + 0x7fffu + ((u >> 16) & 1u)) >> 16;   // RNE
    return (ushort)r;
}

__device__ inline void gload_lds16(const ushort* g, ushort* l) {
    __builtin_amdgcn_global_load_lds(
        (const __attribute__((address_space(1))) void*)g,
        (__attribute__((address_space(3))) void*)l, 16, 0, 0);
}

// ---------------- K1: L2-normalize rows, f32 -> bf16 (+hist in block 0) ----
__global__ void k_normalize(const float* __restrict__ emb,
                            const int* __restrict__ classes,
                            ushort* __restrict__ normed,
                            int* __restrict__ hist, int n) {
    if (blockIdx.x == 0) {                    // class histogram, LDS-only
        __shared__ int h[128];
        if (threadIdx.x < 128) h[threadIdx.x] = 0;
        __syncthreads();
        for (int i = threadIdx.x; i < n; i += 256)
            atomicAdd(&h[classes[i] & 127], 1);
        __syncthreads();
        if (threadIdx.x < 128) hist[threadIdx.x] = h[threadIdx.x];
    }
    int row  = blockIdx.x * 4 + (threadIdx.x >> 6);
    int lane = threadIdx.x & 63;
    if (row >= n) return;
    const float4* src = (const float4*)(emb + (size_t)row * D);
    float4 a = src[lane * 2];
    float4 b = src[lane * 2 + 1];
    float ss = a.x*a.x + a.y*a.y + a.z*a.z + a.w*a.w
             + b.x*b.x + b.y*b.y + b.z*b.z + b.w*b.w;
#pragma unroll
    for (int m = 1; m < 64; m <<= 1) ss += __shfl_xor(ss, m, 64);
    float sc = 1.0f / fmaxf(sqrtf(ss), 1e-12f);
    uint4 o;
    o.x = (unsigned)f2bf(a.x * sc) | ((unsigned)f2bf(a.y * sc) << 16);
    o.y = (unsigned)f2bf(a.z * sc) | ((unsigned)f2bf(a.w * sc) << 16);
    o.z = (unsigned)f2bf(b.x * sc) | ((unsigned)f2bf(b.y * sc) << 16);
    o.w = (unsigned)f2bf(b.z * sc) | ((unsigned)f2bf(b.w * sc) << 16);
    *(uint4*)&normed[(size_t)row * D + lane * 8] = o;
}

// ---------------- K2: 256^2 symmetric masked-exp GEMM ----------------------
// Zpart: plane q in 0..2 (Z,NS,P1), each [32 slots][n rows].
__global__ __launch_bounds__(512, 2) void k_zgemm(
    const ushort* __restrict__ normed, const int* __restrict__ classes,
    float* __restrict__ Zpart, int n, int nb, int npairs) {
    __shared__ char ldsmem[131072];           // A: 2x[256][64], B: same
    __shared__ int clsrow[BT], clscol[BT];
    char* ldsA = ldsmem;
    char* ldsB = ldsmem + 65536;

    const int tid  = threadIdx.x;
    const int lane = tid & 63;
    const int w    = tid >> 6;                 // 0..7
    const int wm   = w >> 2, wn = w & 3;       // 2 x 4 wave grid
    const int l15  = lane & 15, l4 = lane >> 4;
    const size_t QS = (size_t)nb * n;

    // XCD-chunked bijective swizzle (npairs = 528, 528 % 8 == 0)
    int q8 = npairs >> 3, r8 = npairs & 7;
    int xcd = blockIdx.x & 7, off = blockIdx.x >> 3;
    int orig = (xcd < r8 ? xcd * (q8 + 1) : r8 * (q8 + 1) + (xcd - r8) * q8) + off;

    // orig -> (bi,bj) via 8x8 supertile walk
    const int sgrid = nb >> 3;                 // 4
    int idx = orig, si = 0;
    for (;;) { int rc = 36 + (sgrid - 1 - si) * 64; if (idx < rc) break; idx -= rc; ++si; }
    int bi, bj;
    if (idx < 36) { int u = 0, rem = 8; while (idx >= rem) { idx -= rem; ++u; --rem; }
                    bi = si * 8 + u; bj = si * 8 + u + idx; }
    else { idx -= 36; int sj = si + 1 + (idx >> 6); int v = idx & 63;
           bi = si * 8 + (v >> 3); bj = sj * 8 + (v & 7); }
    const int row0 = bi * BT, c0 = bj * BT;
    const bool diagblk = (bi == bj);

    if (tid < BT) clsrow[tid] = classes[row0 + tid];
    else          clscol[tid - BT] = classes[c0 + tid - BT];

    // staging: half-tile = 128 rows x 64 k (16 KB) = 16 chunks of 8 rows;
    // wave w stages chunks {2w, 2w+1}. LDS dest linear (lane*16B); source
    // 16B-slot pre-swizzled: gslot = (lane&7) ^ (lane>>3)  (involution).
    const int gslot = (lane & 7) ^ (lane >> 3);
    const size_t gA0 = (size_t)(row0 + w * 16 + (lane >> 3)) * D + gslot * 8;
    const size_t gB0 = (size_t)(c0   + w * 16 + (lane >> 3)) * D + gslot * 8;
    const int wdst = w * 2048;                 // byte base of wave's chunk pair

    auto STAGE = [&](int mat, int tt, int h) { // matrix 0=A/1=B, K-tile tt, half h
        size_t g = (mat ? gB0 : gA0) + (size_t)h * 128 * D + (size_t)tt * BK;
        char* db = (mat ? ldsB : ldsA) + (tt & 1) * 32768 + h * 16384 + wdst;
        gload_lds16(normed + g,         (ushort*)db);
        gload_lds16(normed + g + 8 * D, (ushort*)(db + 1024));
    };

    f32x4 acc[2][2][4][2];                     // [qr][qc][rf][cf]
#pragma unroll
    for (int a = 0; a < 2; ++a)
#pragma unroll
        for (int b = 0; b < 2; ++b)
#pragma unroll
            for (int c = 0; c < 4; ++c)
#pragma unroll
                for (int d = 0; d < 2; ++d) acc[a][b][c][d] = (f32x4){0.f, 0.f, 0.f, 0.f};

    bf16x8 af[4][2], bf0[2][2], bf1[2][2];

#define LOAD_AF(QR, PA)                                                        \
    _Pragma("unroll") for (int rf = 0; rf < 4; ++rf)                           \
    _Pragma("unroll") for (int ks = 0; ks < 2; ++ks)                           \
        af[rf][ks] = *(const bf16x8*)((PA) + ((QR)*128 + wm*64 + rf*16 + l15)*128 \
                                          + (((ks*4 + l4) ^ (l15 & 7)) << 4));
#define LOAD_BF(DST, QC, PB)                                                   \
    _Pragma("unroll") for (int cf = 0; cf < 2; ++cf)                           \
    _Pragma("unroll") for (int ks = 0; ks < 2; ++ks)                           \
        DST[cf][ks] = *(const bf16x8*)((PB) + ((QC)*128 + wn*32 + cf*16 + l15)*128 \
                                          + (((ks*4 + l4) ^ (l15 & 7)) << 4));
#define MFMA16(QR, QC, BF)                                                     \
    __builtin_amdgcn_s_setprio(1);                                             \
    _Pragma("unroll") for (int rf = 0; rf < 4; ++rf)                           \
    _Pragma("unroll") for (int cf = 0; cf < 2; ++cf)                           \
    _Pragma("unroll") for (int ks = 0; ks < 2; ++ks)                           \
        acc[QR][QC][rf][cf] = __builtin_amdgcn_mfma_f32_16x16x32_bf16(         \
            af[rf][ks], BF[cf][ks], acc[QR][QC][rf][cf], 0, 0, 0);             \
    __builtin_amdgcn_s_setprio(0);
#define PHASE_SYNC                                                             \
    asm volatile("s_waitcnt vmcnt(4)" ::: "memory");                           \
    __builtin_amdgcn_sched_barrier(0);                                         \
    __builtin_amdgcn_s_barrier();                                              \
    __builtin_amdgcn_sched_barrier(0);

    // prologue: K-tile 0's four half-tiles (order fixes the vmcnt mapping)
    STAGE(0, 0, 0); STAGE(1, 0, 0); STAGE(0, 0, 1); STAGE(1, 0, 1);

#pragma unroll
    for (int t = 0; t < NKT; ++t) {
        const char* pA = ldsA + (t & 1) * 32768;
        const char* pB = ldsB + (t & 1) * 32768;
        // P0: Q(0,0)
        PHASE_SYNC
        if (t + 1 < NKT) STAGE(0, t + 1, 0);
        LOAD_AF(0, pA)
        LOAD_BF(bf0, 0, pB)
        MFMA16(0, 0, bf0)
        // P1: Q(1,0)
        PHASE_SYNC
        if (t + 1 < NKT) STAGE(1, t + 1, 0);
        LOAD_AF(1, pA)
        MFMA16(1, 0, bf0)
        // P2: Q(1,1)
        PHASE_SYNC
        if (t + 1 < NKT) STAGE(0, t + 1, 1);
        LOAD_BF(bf1, 1, pB)
        MFMA16(1, 1, bf1)
        // P3: Q(0,1)
        PHASE_SYNC
        if (t + 1 < NKT) STAGE(1, t + 1, 1);
        LOAD_AF(0, pA)
        MFMA16(0, 1, bf1)
    }
    __syncthreads();                           // full drain before LDS overlay

    // ---- epilogue: masked accumulation of (Z, NS, P1) ----
    float cz[2][2] = {{0,0},{0,0}}, cn_[2][2] = {{0,0},{0,0}}, cp[2][2] = {{0,0},{0,0}};
    float* redr = (float*)ldsmem;              // [4 wn][256][3] = 12 KB
    float* redc = (float*)(ldsmem + 12288);    // [2 wm][256][3] = 6 KB

#pragma unroll
    for (int qr = 0; qr < 2; ++qr)
#pragma unroll
    for (int rf = 0; rf < 4; ++rf)
#pragma unroll
    for (int r = 0; r < 4; ++r) {
        int rr = qr * 128 + wm * 64 + rf * 16 + l4 * 4 + r;
        int rg = row0 + rr;
        int cr = clsrow[rr];
        float z = 0.f, ns = 0.f, p1 = 0.f;
#pragma unroll
        for (int qc = 0; qc < 2; ++qc)
#pragma unroll
        for (int cf = 0; cf < 2; ++cf) {
            int cc = qc * 128 + wn * 32 + cf * 16 + l15;
            float tt = fmaf(acc[qr][qc][rf][cf][r], TAUINV, -SHIFT);
            float e = __expf(tt);
            bool same = (cr == clscol[cc]);
            bool dg   = (rg == c0 + cc);
            if (!same)       { z += e;  cz[qc][cf] += e; }
            else if (!dg)    { ns += tt; p1 += e; cn_[qc][cf] += tt; cp[qc][cf] += e; }
        }
#pragma unroll
        for (int m = 1; m < 16; m <<= 1) {
            z  += __shfl_xor(z,  m, 16);
            ns += __shfl_xor(ns, m, 16);
            p1 += __shfl_xor(p1, m, 16);
        }
        if (l15 == 0) {
            float* p = &redr[(wn * 256 + rr) * 3];
            p[0] = z; p[1] = ns; p[2] = p1;
        }
    }
    if (!diagblk) {
#pragma unroll
        for (int qc = 0; qc < 2; ++qc)
#pragma unroll
        for (int cf = 0; cf < 2; ++cf) {
            float z = cz[qc][cf], nv = cn_[qc][cf], p = cp[qc][cf];
            z  += __shfl_xor(z, 16, 64);  z  += __shfl_xor(z, 32, 64);
            nv += __shfl_xor(nv, 16, 64); nv += __shfl_xor(nv, 32, 64);
            p  += __shfl_xor(p, 16, 64);  p  += __shfl_xor(p, 32, 64);
            if (l4 == 0) {
                int cc = qc * 128 + wn * 32 + cf * 16 + l15;
                float* pp = &redc[(wm * 256 + cc) * 3];
                pp[0] = z; pp[1] = nv; pp[2] = p;
            }
        }
    }
    __syncthreads();

    if (tid < BT) {                            // row-side partials, slot = bj
#pragma unroll
        for (int q = 0; q < 3; ++q)
            Zpart[q * QS + (size_t)bj * n + row0 + tid] =
                redr[(0 * 256 + tid) * 3 + q] + redr[(1 * 256 + tid) * 3 + q] +
                redr[(2 * 256 + tid) * 3 + q] + redr[(3 * 256 + tid) * 3 + q];
    } else if (!diagblk) {                     // col-side partials, slot = bi
        int cc = tid - BT;
#pragma unroll
        for (int q = 0; q < 3; ++q)
            Zpart[q * QS + (size_t)bi * n + c0 + cc] =
                redc[(0 * 256 + cc) * 3 + q] + redc[(1 * 256 + cc) * 3 + q];
    }
#undef LOAD_AF
#undef LOAD_BF
#undef MFMA16
#undef PHASE_SYNC
}

// ---------------- K3: per-row closed-form terms ----------------
__global__ void k_rowterms(const float* __restrict__ Zpart,
                           const int* __restrict__ classes,
                           const int* __restrict__ hist,
                           float* __restrict__ rowloss,
                           float* __restrict__ rowcnt, int n, int nslot) {
    int i = blockIdx.x * 256 + threadIdx.x;
    if (i >= n) return;
    const size_t QS = (size_t)nslot * n;
    float z = 0.f, ns = 0.f, p1 = 0.f;
    for (int s = 0; s < nslot; ++s) {
        size_t o = (size_t)s * n + i;
        z  += Zpart[o];
        ns += Zpart[QS + o];
        p1 += Zpart[2 * QS + o];
    }
    float c = (float)(hist[classes[i] & 127] - 1);
    rowloss[i] = -ns + c * logf(z) + p1 / z;
    rowcnt[i]  = c;
}

// ---------------- K4: final deterministic reduction ----------------
__global__ void k_final(const float* __restrict__ rowloss,
                        const float* __restrict__ rowcnt,
                        float* __restrict__ out, int n) {
    __shared__ float sl[1024];
    __shared__ float sc[1024];
    float l = 0.f, c = 0.f;
    for (int i = threadIdx.x; i < n; i += 1024) {
        l += rowloss[i];
        c += rowcnt[i];
    }
    sl[threadIdx.x] = l;
    sc[threadIdx.x] = c;
    __syncthreads();
    for (int s = 512; s > 0; s >>= 1) {
        if (threadIdx.x < s) {
            sl[threadIdx.x] += sl[threadIdx.x + s];
            sc[threadIdx.x] += sc[threadIdx.x + s];
        }
        __syncthreads();
    }
    if (threadIdx.x == 0)
        out[0] = (sc[0] > 0.f) ? sl[0] / sc[0] : 0.f;
}

extern "C" void kernel_launch(void* const* d_in, const int* in_sizes, int n_in,
                              void* d_out, int out_size, void* d_ws, size_t ws_size,
                              hipStream_t stream) {
    const float* emb     = (const float*)d_in[0];
    const int*   classes = (const int*)d_in[1];
    float*       out     = (float*)d_out;
    const int n  = in_sizes[1];               // 8192
    const int nb = n / BT;                    // 32
    const int npairs = nb * (nb + 1) / 2;     // 528

    ushort* normed  = (ushort*)d_ws;                                   // 8 MB
    float*  Zpart   = (float*)((char*)d_ws + (size_t)n * D * 2);       // 3 MB
    float*  rowloss = Zpart + (size_t)3 * nb * n;
    float*  rowcnt  = rowloss + n;
    int*    hist    = (int*)(rowcnt + n);                              // 512 B

    k_normalize<<<n / 4, 256, 0, stream>>>(emb, classes, normed, hist, n);
    k_zgemm<<<npairs, 512, 0, stream>>>(normed, classes, Zpart, n, nb, npairs);
    k_rowterms<<<(n + 255) / 256, 256, 0, stream>>>(Zpart, classes, hist, rowloss, rowcnt, n, nb);
    k_final<<<1, 1024, 0, stream>>>(rowloss, rowcnt, out, n);
}